// Round 7
// baseline (200.698 us; speedup 1.0000x reference)
//
#include <hip/hip_runtime.h>
#include <math.h>

#define BATCH 65536
#define LHIST 128
#define HFUT  32

__device__ __forceinline__ float softplusf(float x) {
    // log(1+e^x), numerically stable; matches jax.nn.softplus (uniform, runs once)
    return fmaxf(x, 0.0f) + log1pf(expf(-fabsf(x)));
}

// 65536 threads = 1024 waves = structurally 1 wave/SIMD (no TLP).
// KEY CHANGE vs all prior rounds: the time loop is ROLLED, not unrolled.
// Fully-unrolled versions are ~120KB of straight-line code executed once per
// wave -> zero I$ reuse, ~6cy/inst instruction-fetch stall (the unexplained
// ~630cy/step in r0's counters). This version's hot loops are ~3KB each
// (I$-resident). Depth-1 software pipeline: group g+1's three float4 loads
// are loop-carried registers issued at the top of iteration g, covered by
// ~1300cy of group-g compute (> ~900cy HBM latency). No LDS, no asm pins,
// no big arrays (r4's spill lesson), streamed stores (clean in r0).
__global__ __launch_bounds__(256, 1) void kalman_fwd(
    const float* __restrict__ v_hist,
    const float* __restrict__ dt_hist,
    const float* __restrict__ x_obs,
    const float* __restrict__ v_fut,
    const float* __restrict__ dt_fut,
    const float* __restrict__ theta,
    float* __restrict__ out)
{
    const int b = blockIdx.x * blockDim.x + threadIdx.x;

    // ---- uniform parameter transforms (once per thread, wave-uniform) ----
    const float alpha = 1.0f / (1.0f + expf(-theta[0]));
    const float c     = softplusf(theta[1]);
    const float kappa = softplusf(theta[2]);
    const float vc    = softplusf(theta[3]);       // VC_MIN = 0
    const float qx    = expf(theta[4]);
    const float qu    = expf(theta[5]);
    const float Rn    = expf(theta[6]);
    const float qs    = expf(theta[7]);
    const float p0xx  = expf(theta[8]);
    const float p0uu  = expf(theta[9]);
    const float a1    = softplusf(theta[10]);
    const float d1    = softplusf(theta[11]);
    const float d2    = softplusf(theta[12]);
    const float d3    = softplusf(theta[13]);
    const float b1    = theta[14];
    const float b2    = theta[15];
    const float beta  = theta[16];
    const float rho_m = tanhf(theta[17]);
    const float qm    = expf(theta[18]);
    const float p0mm  = expf(theta[19]);
    const float vc2   = vc * vc;
    const float qxs   = qs * qx;
    const float qus   = qs * qu;
    const float rm2   = rho_m * rho_m;
    const float nal2e = -alpha * 1.44269504088896340736f;  // exp(-a*dt)=exp2(nal2e*dt)

    // ---- per-thread state: s = (x,u,m); P symmetric 3x3 (6 uniques) ----
    float sx = 0.0f, su = 0.0f, sm = 0.0f;
    float p00 = p0xx, p01 = 0.0f, p02 = 0.0f, p11 = p0uu, p12 = 0.0f, p22 = p0mm;

    auto predict = [&](float v, float dv, float dt_raw) {
        float dt  = fmaxf(dt_raw, 1e-6f);
        float rho = __builtin_amdgcn_exp2f(nal2e * dt);
        float forcing = fmaxf(v * v - vc2, 0.0f);
        float cl = -a1 * su + b1 * v + b2 * dv
                 - d1 * su * su - d2 * su * fabsf(v) - d3 * su * fabsf(su);
        float kdt = kappa * dt;
        float x_p = sx + su * dt;
        float u_p = rho * su - kdt * sx + c * forcing * dt + cl * dt + beta * sm;
        float m_p = rho_m * sm;
        // F = [[1,dt,0],[-kdt,rho,beta],[0,0,rho_m]];  P_p = F P F^T + diag(q)
        float f0 = p00 + dt * p01;
        float f1 = p01 + dt * p11;
        float f2 = p02 + dt * p12;
        float g0 = -kdt * p00 + rho * p01 + beta * p02;
        float g1 = -kdt * p01 + rho * p11 + beta * p12;
        float g2 = -kdt * p02 + rho * p12 + beta * p22;
        float n00 = f0 + dt * f1 + qxs * dt;
        float n01 = -kdt * f0 + rho * f1 + beta * f2;
        float n02 = rho_m * f2;
        float n11 = -kdt * g0 + rho * g1 + beta * g2 + qus * dt;
        float n12 = rho_m * g2;
        float n22 = rm2 * p22 + qm;
        sx = x_p; su = u_p; sm = m_p;
        p00 = n00; p01 = n01; p02 = n02; p11 = n11; p12 = n12; p22 = n22;
    };

    auto update = [&](float y) {
        float innov = y - sx;
        float S    = p00 + Rn;
        float Sinv = __builtin_amdgcn_rcpf(S);
        float K0 = p00 * Sinv, K1 = p01 * Sinv, K2 = p02 * Sinv;
        sx += K0 * innov; su += K1 * innov; sm += K2 * innov;
        float a = 1.0f - K0;
        float n00 = a * a * p00 + Rn * K0 * K0;
        float n01 = a * (p01 - K1 * p00) + Rn * K0 * K1;
        float n02 = a * (p02 - K2 * p00) + Rn * K0 * K2;
        float n11 = S * K1 * K1 - 2.0f * K1 * p01 + p11;
        float n12 = S * K1 * K2 - K2 * p01 - K1 * p02 + p12;
        float n22 = S * K2 * K2 - 2.0f * K2 * p02 + p22;
        p00 = n00; p01 = n01; p02 = n02; p11 = n11; p12 = n12; p22 = n22;
    };

    const float4* v4 = (const float4*)(v_hist  + (size_t)b * LHIST);
    const float4* d4 = (const float4*)(dt_hist + (size_t)b * LHIST);
    const float4* y4 = (const float4*)(x_obs   + (size_t)b * LHIST);

    // rolling v-carry: vp1 = v[t'-1], vp2 = v[t'-2]; step t' does
    // predict(v[t'-1], v[t'-1]-v[t'-2], dt[t']); update(y[t'])
    float vp1, vp2;

    // ---- history group 0 (peeled: init at t'=0, then t'=1..3) ----
    float4 cvv = v4[0], cdd = d4[0], cyy = y4[0];
    float4 pv  = v4[1], pd  = d4[1], py  = y4[1];   // prefetch g=1
    {
        const float* vv = (const float*)&cvv;
        const float* dd = (const float*)&cdd;
        const float* yy = (const float*)&cyy;
        sx = yy[0]; vp1 = vv[0]; vp2 = vv[0];
        #pragma unroll
        for (int m = 1; m < 4; ++m) {
            float vcur = vv[m];
            predict(vp1, vp1 - vp2, dd[m]);
            update(yy[m]);
            vp2 = vp1; vp1 = vcur;
        }
    }

    // ---- history groups 1..31 (rolled; ~3KB body, I$-resident).
    // Loads for g+1 are loop-carried: issued here, consumed next iteration.
    #pragma unroll 1
    for (int g = 1; g < LHIST / 4; ++g) {
        cvv = pv; cdd = pd; cyy = py;
        int gn = (g < LHIST / 4 - 1) ? g + 1 : g;   // clamp: last iter re-loads (L2 hit)
        pv = v4[gn]; pd = d4[gn]; py = y4[gn];
        const float* vv = (const float*)&cvv;
        const float* dd = (const float*)&cdd;
        const float* yy = (const float*)&cyy;
        #pragma unroll
        for (int m = 0; m < 4; ++m) {
            float vcur = vv[m];
            predict(vp1, vp1 - vp2, dd[m]);
            update(yy[m]);
            vp2 = vp1; vp1 = vcur;
        }
    }
    // steps t'=0..127 done; vp1 = v_hist[b][127]

    // ---- future rollout: rolled loop over 8 groups of 4 predicts ----
    const float4* vf4 = (const float4*)(v_fut  + (size_t)b * HFUT);
    const float4* df4 = (const float4*)(dt_fut + (size_t)b * HFUT);
    float4* xp = (float4*)(out + (size_t)b * HFUT);
    float4* xv = (float4*)(out + (size_t)BATCH * HFUT + (size_t)b * HFUT);
    float4* ue = (float4*)(out + 2 * (size_t)BATCH * HFUT + (size_t)b * HFUT);

    float vp = vp1;
    float4 fv = vf4[0], fd = df4[0];                // current future group
    float4 qv = vf4[1], qd = df4[1];                // prefetched next group
    #pragma unroll 1
    for (int g = 0; g < HFUT / 4; ++g) {
        const float* vv = (const float*)&fv;
        const float* dd = (const float*)&fd;
        float4 ox, ov, ou;
        float* oxp = (float*)&ox; float* ovp = (float*)&ov; float* oup = (float*)&ou;
        #pragma unroll
        for (int m = 0; m < 4; ++m) {
            predict(vv[m], vv[m] - vp, dd[m]);
            vp = vv[m];
            oxp[m] = sx; ovp[m] = p00; oup[m] = su;
        }
        xp[g] = ox; xv[g] = ov; ue[g] = ou;         // streamed 16B stores (clean in r0)
        fv = qv; fd = qd;
        int gn = (g < HFUT / 4 - 2) ? g + 2 : HFUT / 4 - 1;
        qv = vf4[gn]; qd = df4[gn];
    }
}

extern "C" void kernel_launch(void* const* d_in, const int* in_sizes, int n_in,
                              void* d_out, int out_size, void* d_ws, size_t ws_size,
                              hipStream_t stream) {
    const float* v_hist  = (const float*)d_in[0];
    const float* dt_hist = (const float*)d_in[1];
    const float* x_obs   = (const float*)d_in[2];
    const float* v_fut   = (const float*)d_in[3];
    const float* dt_fut  = (const float*)d_in[4];
    const float* theta   = (const float*)d_in[5];
    float* out = (float*)d_out;

    dim3 grid(BATCH / 256), block(256);
    hipLaunchKernelGGL(kalman_fwd, grid, block, 0, stream,
                       v_hist, dt_hist, x_obs, v_fut, dt_fut, theta, out);
}

// Round 8
// 179.556 us; speedup vs baseline: 1.1177x; 1.1177x over previous
//
#include <hip/hip_runtime.h>
#include <math.h>

#define BATCH 65536
#define LHIST 128
#define HFUT  32

__device__ __forceinline__ float softplusf(float x) {
    // log(1+e^x), numerically stable; matches jax.nn.softplus (uniform, runs once)
    return fmaxf(x, 0.0f) + log1pf(expf(-fabsf(x)));
}

// K ring buffer in LDS: [2 bufs][16 steps][3 comps][256 rows] floats = 96 KiB.
// Lane->row is stride-1 -> conflict-free (2 lanes/bank, free on CDNA4).
#define KSLOT(buf, st, c, row) ((((((buf)*16 + (st))*3 + (c))*256)) + (row))

// THE INSIGHT (from 7 rounds of counters): every 1-thread-per-row variant
// pins at VALUBusy ~33% -- a single wave/SIMD executing a serial recurrence
// pays ~6cy/dependent-inst (2cy issue + 4cy bubble) and NOTHING in-wave can
// fill the bubbles. But the Kalman covariance recursion is STATE-INDEPENDENT:
// P/K depend only on dt. So: 2 threads per row (131072 threads = 2 waves/SIMD).
//   P-thread: covariance + gains (heavy), writes (K0,K1,K2) to an LDS ring.
//   s-thread: state recursion (light), consumes K one chunk behind.
// Same total VALU work, two independent streams per SIMD -> bubbles filled.
// Arithmetic is identical to the verified 1-thread kernel, just partitioned.
__global__ __launch_bounds__(512, 2) void kalman_fwd(
    const float* __restrict__ v_hist,
    const float* __restrict__ dt_hist,
    const float* __restrict__ x_obs,
    const float* __restrict__ v_fut,
    const float* __restrict__ dt_fut,
    const float* __restrict__ theta,
    float* __restrict__ out)
{
    const int tid = threadIdx.x;
    const bool isP = (tid < 256);          // waves 0-3: P-role; waves 4-7: s-role
    const int row  = tid & 255;
    const int b    = blockIdx.x * 256 + row;

    __shared__ float Kls[2 * 16 * 3 * 256];   // 96 KiB -> 1 block/CU, 8 waves = 2/SIMD

    // ---- uniform parameter transforms (once per thread, wave-uniform) ----
    const float alpha = 1.0f / (1.0f + expf(-theta[0]));
    const float c     = softplusf(theta[1]);
    const float kappa = softplusf(theta[2]);
    const float vc    = softplusf(theta[3]);       // VC_MIN = 0
    const float qx    = expf(theta[4]);
    const float qu    = expf(theta[5]);
    const float Rn    = expf(theta[6]);
    const float qs    = expf(theta[7]);
    const float p0xx  = expf(theta[8]);
    const float p0uu  = expf(theta[9]);
    const float a1    = softplusf(theta[10]);
    const float d1    = softplusf(theta[11]);
    const float d2    = softplusf(theta[12]);
    const float d3    = softplusf(theta[13]);
    const float b1    = theta[14];
    const float b2    = theta[15];
    const float beta  = theta[16];
    const float rho_m = tanhf(theta[17]);
    const float qm    = expf(theta[18]);
    const float p0mm  = expf(theta[19]);
    const float vc2   = vc * vc;
    const float qxs   = qs * qx;
    const float qus   = qs * qu;
    const float rm2   = rho_m * rho_m;
    const float nal2e = -alpha * 1.44269504088896340736f;  // exp(-a*dt)=exp2(nal2e*dt)

    // ---- P-role state: P symmetric 3x3 (6 uniques) ----
    float p00 = p0xx, p01 = 0.0f, p02 = 0.0f, p11 = p0uu, p12 = 0.0f, p22 = p0mm;
    // ---- s-role state: s = (x,u,m) + rolling v carry ----
    float sx = 0.0f, su = 0.0f, sm = 0.0f, vp1 = 0.0f, vp2 = 0.0f;

    // P predict+update for one history step; writes K to ring slot (buf, st)
    auto P_step = [&](float dt_raw, int buf, int st) {
        float dt  = fmaxf(dt_raw, 1e-6f);
        float rho = __builtin_amdgcn_exp2f(nal2e * dt);
        float kdt = kappa * dt;
        float f0 = p00 + dt * p01;
        float f1 = p01 + dt * p11;
        float f2 = p02 + dt * p12;
        float g0 = -kdt * p00 + rho * p01 + beta * p02;
        float g1 = -kdt * p01 + rho * p11 + beta * p12;
        float g2 = -kdt * p02 + rho * p12 + beta * p22;
        float n00 = f0 + dt * f1 + qxs * dt;
        float n01 = -kdt * f0 + rho * f1 + beta * f2;
        float n02 = rho_m * f2;
        float n11 = -kdt * g0 + rho * g1 + beta * g2 + qus * dt;
        float n12 = rho_m * g2;
        float n22 = rm2 * p22 + qm;
        float S    = n00 + Rn;
        float Sinv = __builtin_amdgcn_rcpf(S);
        float K0 = n00 * Sinv, K1 = n01 * Sinv, K2 = n02 * Sinv;
        Kls[KSLOT(buf, st, 0, row)] = K0;
        Kls[KSLOT(buf, st, 1, row)] = K1;
        Kls[KSLOT(buf, st, 2, row)] = K2;
        float a = 1.0f - K0;
        p00 = a * a * n00 + Rn * K0 * K0;
        p01 = a * (n01 - K1 * n00) + Rn * K0 * K1;
        p02 = a * (n02 - K2 * n00) + Rn * K0 * K2;
        p11 = S * K1 * K1 - 2.0f * K1 * n01 + n11;
        p12 = S * K1 * K2 - K2 * n01 - K1 * n02 + n12;
        p22 = S * K2 * K2 - 2.0f * K2 * n02 + n22;
    };

    // P predict only (future rollout)
    auto P_pred = [&](float dt_raw) {
        float dt  = fmaxf(dt_raw, 1e-6f);
        float rho = __builtin_amdgcn_exp2f(nal2e * dt);
        float kdt = kappa * dt;
        float f0 = p00 + dt * p01;
        float f1 = p01 + dt * p11;
        float f2 = p02 + dt * p12;
        float g0 = -kdt * p00 + rho * p01 + beta * p02;
        float g1 = -kdt * p01 + rho * p11 + beta * p12;
        float g2 = -kdt * p02 + rho * p12 + beta * p22;
        float n00 = f0 + dt * f1 + qxs * dt;
        float n01 = -kdt * f0 + rho * f1 + beta * f2;
        float n02 = rho_m * f2;
        float n11 = -kdt * g0 + rho * g1 + beta * g2 + qus * dt;
        float n12 = rho_m * g2;
        float n22 = rm2 * p22 + qm;
        p00 = n00; p01 = n01; p02 = n02; p11 = n11; p12 = n12; p22 = n22;
    };

    // s predict (uses rolling v carry) -- no P dependence
    auto s_pred = [&](float v, float dv, float dt_raw) {
        float dt  = fmaxf(dt_raw, 1e-6f);
        float rho = __builtin_amdgcn_exp2f(nal2e * dt);
        float forcing = fmaxf(v * v - vc2, 0.0f);
        float cl = -a1 * su + b1 * v + b2 * dv
                 - d1 * su * su - d2 * su * fabsf(v) - d3 * su * fabsf(su);
        float kdt = kappa * dt;
        float x_p = sx + su * dt;
        float u_p = rho * su - kdt * sx + c * forcing * dt + cl * dt + beta * sm;
        float m_p = rho_m * sm;
        sx = x_p; su = u_p; sm = m_p;
    };

    // s history step: predict + K-gain update (K from LDS ring)
    auto s_step = [&](float vnew, float dt_raw, float y, int buf, int st) {
        float K0 = Kls[KSLOT(buf, st, 0, row)];
        float K1 = Kls[KSLOT(buf, st, 1, row)];
        float K2 = Kls[KSLOT(buf, st, 2, row)];
        s_pred(vp1, vp1 - vp2, dt_raw);
        float innov = y - sx;
        sx += K0 * innov; su += K1 * innov; sm += K2 * innov;
        vp2 = vp1; vp1 = vnew;
    };

    const float4* v4 = (const float4*)(v_hist  + (size_t)b * LHIST);
    const float4* d4 = (const float4*)(dt_hist + (size_t)b * LHIST);
    const float4* y4 = (const float4*)(x_obs   + (size_t)b * LHIST);

    // ================= history: pipelined P->s over 8 chunks of 16 =========
    // iteration k: P computes chunk k into buf[k&1]; s consumes chunk k-1
    // from buf[(k-1)&1]. One barrier per iteration; all waves same sequence.
    {
        // ---- prologue (k=0): P does chunk 0 (steps t'=1..15); s idle ----
        if (isP) {
            float cdt[16];
            float4* C = (float4*)cdt;
            #pragma unroll
            for (int i = 0; i < 4; ++i) C[i] = d4[i];
            #pragma unroll
            for (int st = 1; st < 16; ++st) P_step(cdt[st], 0, st);
        }
        __syncthreads();

        #pragma unroll 1
        for (int k = 1; k < 8; ++k) {
            if (isP) {
                float cdt[16];
                float4* C = (float4*)cdt;
                #pragma unroll
                for (int i = 0; i < 4; ++i) C[i] = d4[k * 4 + i];
                int buf = k & 1;
                P_step(cdt[0], buf, 0);
                #pragma unroll
                for (int st = 1; st < 16; ++st) P_step(cdt[st], buf, st);
            } else {
                int j = k - 1;                      // chunk s consumes
                float cv[16], cd[16], cy[16];
                float4* V = (float4*)cv; float4* D = (float4*)cd; float4* Y = (float4*)cy;
                #pragma unroll
                for (int i = 0; i < 4; ++i) {
                    V[i] = v4[j * 4 + i]; D[i] = d4[j * 4 + i]; Y[i] = y4[j * 4 + i];
                }
                int buf = j & 1;
                if (j == 0) {
                    sx = cy[0]; vp1 = cv[0]; vp2 = cv[0];   // t'=0 init
                } else {
                    s_step(cv[0], cd[0], cy[0], buf, 0);
                }
                #pragma unroll
                for (int st = 1; st < 16; ++st) s_step(cv[st], cd[st], cy[st], buf, st);
            }
            __syncthreads();
        }

        // ---- epilogue: s consumes chunk 7 (P is already free to run future) --
        if (!isP) {
            const int j = 7;
            float cv[16], cd[16], cy[16];
            float4* V = (float4*)cv; float4* D = (float4*)cd; float4* Y = (float4*)cy;
            #pragma unroll
            for (int i = 0; i < 4; ++i) {
                V[i] = v4[j * 4 + i]; D[i] = d4[j * 4 + i]; Y[i] = y4[j * 4 + i];
            }
            s_step(cv[0], cd[0], cy[0], 1, 0);
            #pragma unroll
            for (int st = 1; st < 16; ++st) s_step(cv[st], cd[st], cy[st], 1, st);
        }
    }
    // history done: s-threads hold state after 127 steps, vp1 = v_hist[b][127];
    // P-threads hold post-update P after step 127. No further communication.

    // ================= future rollout (32 predicts, roles independent) =====
    if (isP) {
        float fdt[32];
        float4* FD = (float4*)fdt;
        const float4* df4 = (const float4*)(dt_fut + (size_t)b * HFUT);
        #pragma unroll
        for (int i = 0; i < 8; ++i) FD[i] = df4[i];
        float oxv[32];
        #pragma unroll
        for (int j = 0; j < HFUT; ++j) { P_pred(fdt[j]); oxv[j] = p00; }
        // grouped back-to-back burst stores (the only clean-WRITE pattern seen)
        float4* xv = (float4*)(out + (size_t)BATCH * HFUT + (size_t)b * HFUT);
        float4* OXV = (float4*)oxv;
        #pragma unroll
        for (int i = 0; i < 8; ++i) xv[i] = OXV[i];
    } else {
        float fv[32], fdt[32];
        float4* FV = (float4*)fv; float4* FD = (float4*)fdt;
        const float4* vf4 = (const float4*)(v_fut  + (size_t)b * HFUT);
        const float4* df4 = (const float4*)(dt_fut + (size_t)b * HFUT);
        #pragma unroll
        for (int i = 0; i < 8; ++i) { FV[i] = vf4[i]; FD[i] = df4[i]; }
        float oxp[32], oue[32];
        float vp = vp1;
        #pragma unroll
        for (int j = 0; j < HFUT; ++j) {
            s_pred(fv[j], fv[j] - vp, fdt[j]);
            vp = fv[j];
            oxp[j] = sx; oue[j] = su;
        }
        float4* xp = (float4*)(out + (size_t)b * HFUT);
        float4* ue = (float4*)(out + 2 * (size_t)BATCH * HFUT + (size_t)b * HFUT);
        float4* OXP = (float4*)oxp; float4* OUE = (float4*)oue;
        #pragma unroll
        for (int i = 0; i < 8; ++i) { xp[i] = OXP[i]; ue[i] = OUE[i]; }
    }
}

extern "C" void kernel_launch(void* const* d_in, const int* in_sizes, int n_in,
                              void* d_out, int out_size, void* d_ws, size_t ws_size,
                              hipStream_t stream) {
    const float* v_hist  = (const float*)d_in[0];
    const float* dt_hist = (const float*)d_in[1];
    const float* x_obs   = (const float*)d_in[2];
    const float* v_fut   = (const float*)d_in[3];
    const float* dt_fut  = (const float*)d_in[4];
    const float* theta   = (const float*)d_in[5];
    float* out = (float*)d_out;

    // 256 blocks x 512 threads: 2 threads per batch row -> 2048 waves
    // = 2 waves/SIMD (vs 1 before): the occupancy unlock.
    dim3 grid(BATCH / 256), block(512);
    hipLaunchKernelGGL(kalman_fwd, grid, block, 0, stream,
                       v_hist, dt_hist, x_obs, v_fut, dt_fut, theta, out);
}